// Round 9
// baseline (92.210 us; speedup 1.0000x reference)
//
#include <hip/hip_runtime.h>
#include <math.h>

#define NCODE 64
#define SIGMA 10.0f
#define LOG2E 1.4426950408889634f
#define BLK 256
#define PPT 2

// Round-9: R8 minus the wave-uniform FP redone per thread. A 1-block setup
// kernel precomputes (e0, e1, n_j) into a d_ws const buffer; the main loop
// reads it as one s_load_dwordx4 per j (SALU/K$ path, zero VALU) instead of
// rebuilding n_j with 3 VALU per j per thread (SALU has no FP pipe).
// Fused single pass, e[64] float2 in registers, fully-unrolled constant
// indexing (dynamic index => scratch demotion, rounds 1/5 lesson), compacted
// butterfly, two-stage deterministic reduce.
__global__ void vq_setup(const float* __restrict__ embed,
                         float4* __restrict__ cbuf) {
    const int j = threadIdx.x;          // 64 threads
    float e0 = embed[2 * j];
    float e1 = embed[2 * j + 1];
    // n_j exactly as np: rn(rn(e0*e0) + rn(e1*e1))
    float n = __fadd_rn(__fmul_rn(e0, e0), __fmul_rn(e1, e1));
    cbuf[j] = make_float4(e0, e1, n, 0.0f);
}

__global__ __launch_bounds__(BLK, 3) void vq_main(
    const float* __restrict__ x,
    const float* __restrict__ embed,
    const float4* __restrict__ cb,      // [64] (e0, e1, n_j, 0) precomputed
    float* __restrict__ out_q,          // [npts*2] fp32
    float* __restrict__ partial)        // [nblk*64] fp32 (d_ws)
{
    __shared__ float sred[BLK / 64][NCODE];

    const int t      = threadIdx.x;
    const int gid    = blockIdx.x * BLK + t;
    const int stride = gridDim.x * BLK;          // 524288
    const float2* __restrict__ xp = (const float2*)x;
    const float2* __restrict__ ep = (const float2*)embed;
    float2* __restrict__ qp = (float2*)out_q;

    const int i1 = gid;
    const int i2 = gid + stride;
    float2 p1 = xp[i1];
    float2 p2 = xp[i2];
    // s exactly as np: rn(rn(p0*p0) + rn(p1*p1))
    float s1 = __fadd_rn(__fmul_rn(p1.x, p1.x), __fmul_rn(p1.y, p1.y));
    float s2 = __fadd_rn(__fmul_rn(p2.x, p2.x), __fmul_rn(p2.y, p2.y));

    // ---- fused pass: bit-exact logit -> argmax track + inline exp ----
    float2 e[NCODE];                    // (.x = point1 term, .y = point2 term)
    float m1 = -INFINITY, m2 = -INFINITY;
    int b1 = 0, b2 = 0;
    float ss1 = 0.0f, ss2 = 0.0f;
#pragma unroll
    for (int j = 0; j < NCODE; ++j) {
        float4 c = cb[j];               // wave-uniform -> s_load_dwordx4 (K$)
        // np sgemm model (OpenBLAS K=2): dot = fma(p1,e1, rn(p0*e0))
        float dot1 = fmaf(p1.y, c.y, __fmul_rn(p1.x, c.x));
        float dot2 = fmaf(p2.y, c.y, __fmul_rn(p2.x, c.x));
        // d = rn(rn(s - 2*dot) + n); fma(-2,dot,s) rounds once == fsub of exact 2*dot
        float d1 = __fadd_rn(fmaf(-2.0f, dot1, s1), c.z);
        float d2 = __fadd_rn(fmaf(-2.0f, dot2, s2), c.z);
        float l1 = __fmul_rn(-SIGMA, d1);
        float l2 = __fmul_rn(-SIGMA, d2);
        if (l1 > m1) { m1 = l1; b1 = j; }   // strict >: first-occurrence ties
        if (l2 > m2) { m2 = l2; b2 = j; }
        // softmax terms without max-sub (l <= ~0: no overflow; underflow ok)
        float v1 = __builtin_amdgcn_exp2f(__fmul_rn(l1, LOG2E));
        float v2 = __builtin_amdgcn_exp2f(__fmul_rn(l2, LOG2E));
        e[j] = make_float2(v1, v2);
        ss1 += v1;
        ss2 += v2;
    }

    // ---- straight-through forward value: hard_q = embed[argmax] (L1 gather) ----
    {
        float2 cb1 = ep[b1];
        float2 cb2 = ep[b2];
        qp[i1] = cb1;
        qp[i2] = cb2;
    }

    // guard: if every term underflowed (prob ~0), contribute 0 instead of NaN
    const float inv1 = ss1 > 0.0f ? __builtin_amdgcn_rcpf(ss1) : 0.0f;
    const float inv2 = ss2 > 0.0f ? __builtin_amdgcn_rcpf(ss2) : 0.0f;

    // ---- normalize + merge the two points' contributions ----
    float mg[NCODE];
#pragma unroll
    for (int j = 0; j < NCODE; ++j)
        mg[j] = fmaf(e[j].y, inv2, __fmul_rn(e[j].x, inv1));

    // ---- compacted butterfly: 63 shuffles; lane k ends owning wave-sum of bin k ----
    const int lane = t & 63;
#pragma unroll
    for (int step = 32; step >= 1; step >>= 1) {
        const bool upper = (lane & step) != 0;
#pragma unroll
        for (int i = 0; i < step; ++i) {
            float lo = mg[i], hi = mg[i + step];
            float send = upper ? lo : hi;
            float keep = upper ? hi : lo;
            mg[i] = keep + __shfl_xor(send, step, 64);
        }
    }

    // ---- cross-wave combine + coalesced partial write ----
    const int wv = t >> 6;
    sred[wv][lane] = mg[0];
    __syncthreads();
    if (t < NCODE) {
        float tot = sred[0][t] + sred[1][t] + sred[2][t] + sred[3][t];
        partial[blockIdx.x * NCODE + t] = tot;
    }
}

// ---- round-4 kernel kept verbatim as small-ws fallback (needs 256 KB) ----
#define PPT4 4
__global__ __launch_bounds__(BLK, 4) void vq_main4(
    const float* __restrict__ x,
    const float* __restrict__ embed,
    float* __restrict__ out_q,
    float* __restrict__ partial)
{
    __shared__ float4 scode[NCODE];
    __shared__ float4 sfast[NCODE];
    __shared__ float  sred[BLK / 64][NCODE];

    const int t = threadIdx.x;
    if (t < NCODE) {
        float e0 = embed[2 * t];
        float e1 = embed[2 * t + 1];
        float n = __fadd_rn(__fmul_rn(e0, e0), __fmul_rn(e1, e1));
        scode[t] = make_float4(e0, e1, n, 0.0f);
        const float k20  = 20.0f * LOG2E;
        const float km10 = -10.0f * LOG2E;
        sfast[t] = make_float4(k20 * e0, k20 * e1, km10 * n, 0.0f);
    }
    __syncthreads();

    const int gid    = blockIdx.x * BLK + t;
    const int stride = gridDim.x * BLK;
    const float2* __restrict__ xp = (const float2*)x;
    float2* __restrict__ qp = (float2*)out_q;

    float2 p[PPT4]; float s[PPT4]; int idx[PPT4];
#pragma unroll
    for (int k = 0; k < PPT4; ++k) {
        idx[k] = gid + k * stride;
        p[k] = xp[idx[k]];
        s[k] = __fadd_rn(__fmul_rn(p[k].x, p[k].x), __fmul_rn(p[k].y, p[k].y));
    }

    float m[PPT4]; int best[PPT4];
#pragma unroll
    for (int k = 0; k < PPT4; ++k) { m[k] = -INFINITY; best[k] = 0; }
#pragma unroll 8
    for (int j = 0; j < NCODE; ++j) {
        float4 c = scode[j];
#pragma unroll
        for (int k = 0; k < PPT4; ++k) {
            float dot = fmaf(p[k].y, c.y, __fmul_rn(p[k].x, c.x));
            float d = __fadd_rn(fmaf(-2.0f, dot, s[k]), c.z);
            float lg = __fmul_rn(-SIGMA, d);
            if (lg > m[k]) { m[k] = lg; best[k] = j; }
        }
    }
#pragma unroll
    for (int k = 0; k < PPT4; ++k) {
        float4 cbv = scode[best[k]];
        qp[idx[k]] = make_float2(cbv.x, cbv.y);
    }

    float gref[PPT4], ssum[PPT4];
#pragma unroll
    for (int k = 0; k < PPT4; ++k) {
        gref[k] = __fmul_rn(fmaf(10.0f, s[k], m[k]), LOG2E);
        ssum[k] = 0.0f;
    }
#pragma unroll 8
    for (int j = 0; j < NCODE; ++j) {
        float4 f = sfast[j];
#pragma unroll
        for (int k = 0; k < PPT4; ++k) {
            float g = fmaf(p[k].x, f.x, fmaf(p[k].y, f.y, f.z));
            ssum[k] += __builtin_amdgcn_exp2f(g - gref[k]);
        }
    }
#pragma unroll
    for (int k = 0; k < PPT4; ++k)
        gref[k] += __builtin_amdgcn_logf(ssum[k]);

    float acc[NCODE];
#pragma unroll
    for (int j = 0; j < NCODE; ++j) {
        float4 f = sfast[j];
        float tt = 0.0f;
#pragma unroll
        for (int k = 0; k < PPT4; ++k) {
            float g = fmaf(p[k].x, f.x, fmaf(p[k].y, f.y, f.z));
            tt += __builtin_amdgcn_exp2f(g - gref[k]);
        }
        acc[j] = tt;
    }

    const int lane = t & 63;
#pragma unroll
    for (int step = 32; step >= 1; step >>= 1) {
        const bool upper = (lane & step) != 0;
#pragma unroll
        for (int i = 0; i < step; ++i) {
            float lo = acc[i], hi = acc[i + step];
            float send = upper ? lo : hi;
            float keep = upper ? hi : lo;
            acc[i] = keep + __shfl_xor(send, step, 64);
        }
    }
    const int wv = t >> 6;
    sred[wv][lane] = acc[0];
    __syncthreads();
    if (t < NCODE) {
        float tot = sred[0][t] + sred[1][t] + sred[2][t] + sred[3][t];
        partial[blockIdx.x * NCODE + t] = tot;
    }
}

// Stage 2: reduce nblk x 64 partials -> out_lik (no atomics, deterministic).
__global__ __launch_bounds__(256) void vq_reduce(
    const float* __restrict__ partial,
    float* __restrict__ out_lik,
    int nblk, float scale)
{
    __shared__ float sm[4];
    const int b = blockIdx.x;       // bin
    const int t = threadIdx.x;
    float s = 0.0f;
    for (int i = t; i < nblk; i += 256)
        s += partial[i * NCODE + b];
#pragma unroll
    for (int msk = 32; msk >= 1; msk >>= 1)
        s += __shfl_xor(s, msk, 64);
    if ((t & 63) == 0) sm[t >> 6] = s;
    __syncthreads();
    if (t == 0)
        out_lik[b] = (sm[0] + sm[1] + sm[2] + sm[3]) * scale;
}

extern "C" void kernel_launch(void* const* d_in, const int* in_sizes, int n_in,
                              void* d_out, int out_size, void* d_ws, size_t ws_size,
                              hipStream_t stream) {
    (void)n_in;
    const float* x     = (const float*)d_in[0];   // [64*32*32*32] fp32
    const float* embed = (const float*)d_in[1];   // [64*2] fp32

    const int npts = in_sizes[0] / 2;             // 1,048,576 points
    float* out_q   = (float*)d_out;               // [npts*2]
    float* out_lik = (float*)d_out + (out_size - NCODE); // [64] tail
    float* partial = (float*)d_ws;

    const int nblk = npts / (BLK * PPT);          // 2048
    const size_t part_bytes = (size_t)nblk * NCODE * sizeof(float);  // 512 KB
    const size_t need = part_bytes + NCODE * sizeof(float4);         // +1 KB cbuf

    if (ws_size >= need) {
        float4* cbuf = (float4*)((char*)d_ws + part_bytes);
        vq_setup<<<1, NCODE, 0, stream>>>(embed, cbuf);
        vq_main<<<nblk, BLK, 0, stream>>>(x, embed, cbuf, out_q, partial);
        vq_reduce<<<NCODE, 256, 0, stream>>>(partial, out_lik, nblk,
                                             1.0f / (float)npts);
    } else {
        const int nblk4 = npts / (BLK * PPT4);    // 1024 (256 KB ws, round-4 proven)
        vq_main4<<<nblk4, BLK, 0, stream>>>(x, embed, out_q, partial);
        vq_reduce<<<NCODE, 256, 0, stream>>>(partial, out_lik, nblk4,
                                             1.0f / (float)npts);
    }
}

// Round 10
// 89.690 us; speedup vs baseline: 1.0281x; 1.0281x over previous
//
#include <hip/hip_runtime.h>
#include <math.h>

#define NCODE 64
#define SIGMA 10.0f
#define LOG2E 1.4426950408889634f
#define BLK 256
#define PPT 2

// Round-10: R8 two-launch structure (R9's third launch cost ~2.5us > its VALU
// saving) with the j-loop written as explicit lane-pair (float2) expressions
// so SLP can emit v_pk_{mul,fma,add}_f32 — packed halves round identically to
// scalar IEEE, so the bit-exact argmax chain is unchanged. Fused single pass
// (no max-sub: logits <= ~0, overflow impossible, underflow only flushes
// negligible terms), e[64] float2 in registers, FULL unroll everywhere a
// register array is indexed (dynamic index => scratch demotion, rounds 1/5),
// compacted butterfly, deterministic two-stage reduce.
__global__ __launch_bounds__(BLK, 3) void vq_main(
    const float* __restrict__ x,
    const float* __restrict__ embed,
    float* __restrict__ out_q,          // [npts*2] fp32
    float* __restrict__ partial)        // [nblk*64] fp32 (d_ws)
{
    __shared__ float sred[BLK / 64][NCODE];

    const int t      = threadIdx.x;
    const int gid    = blockIdx.x * BLK + t;
    const int stride = gridDim.x * BLK;          // 524288
    const float2* __restrict__ xp = (const float2*)x;
    const float2* __restrict__ ep = (const float2*)embed;
    float2* __restrict__ qp = (float2*)out_q;

    const int i1 = gid;
    const int i2 = gid + stride;
    float2 p1 = xp[i1];
    float2 p2 = xp[i2];
    // s exactly as np: rn(rn(p0*p0) + rn(p1*p1))
    float s1 = __fadd_rn(__fmul_rn(p1.x, p1.x), __fmul_rn(p1.y, p1.y));
    float s2 = __fadd_rn(__fmul_rn(p2.x, p2.x), __fmul_rn(p2.y, p2.y));

    // lane-pair vectors: component = which point (pk-op halves)
    const float2 P0 = make_float2(p1.x, p2.x);   // x-coords of both points
    const float2 P1 = make_float2(p1.y, p2.y);   // y-coords
    const float2 S  = make_float2(s1, s2);

    // ---- fused pass: bit-exact logit -> argmax track + inline exp ----
    float2 e[NCODE];                    // (.x = point1 term, .y = point2 term)
    float m1 = -INFINITY, m2 = -INFINITY;
    int b1 = 0, b2 = 0;
    float2 ss = make_float2(0.0f, 0.0f);
#pragma unroll
    for (int j = 0; j < NCODE; ++j) {
        float2 c = ep[j];               // wave-uniform global load (L1/K$)
        // n_j exactly as np: rn(rn(e0*e0) + rn(e1*e1)) — scalar, shared
        float n = __fadd_rn(__fmul_rn(c.x, c.x), __fmul_rn(c.y, c.y));
        // np sgemm model (OpenBLAS K=2): dot = fma(p1,e1, rn(p0*e0))
        // pk-mul then pk-fma (per-half rounding == scalar rounding)
        float2 dm = make_float2(__fmul_rn(P0.x, c.x), __fmul_rn(P0.y, c.x));
        float2 dt = make_float2(fmaf(P1.x, c.y, dm.x), fmaf(P1.y, c.y, dm.y));
        // d = rn(rn(s - 2*dot) + n); fma(-2,dot,s) rounds once == exact-2dot fsub
        float2 dd = make_float2(fmaf(-2.0f, dt.x, S.x), fmaf(-2.0f, dt.y, S.y));
        float2 d  = make_float2(__fadd_rn(dd.x, n), __fadd_rn(dd.y, n));
        float2 l  = make_float2(__fmul_rn(-SIGMA, d.x), __fmul_rn(-SIGMA, d.y));
        // argmax: scalar, strict > (first-occurrence ties, matches np.argmax)
        if (l.x > m1) { m1 = l.x; b1 = j; }
        if (l.y > m2) { m2 = l.y; b2 = j; }
        // softmax terms without max-sub (l <= ~0: no overflow; underflow ok)
        float2 ea = make_float2(__fmul_rn(l.x, LOG2E), __fmul_rn(l.y, LOG2E));
        float2 v  = make_float2(__builtin_amdgcn_exp2f(ea.x),
                                __builtin_amdgcn_exp2f(ea.y));
        e[j] = v;
        ss = make_float2(__fadd_rn(ss.x, v.x), __fadd_rn(ss.y, v.y));
    }

    // ---- straight-through forward value: hard_q = embed[argmax] (L1 gather) ----
    {
        float2 cb1 = ep[b1];
        float2 cb2 = ep[b2];
        qp[i1] = cb1;
        qp[i2] = cb2;
    }

    // guard: if every term underflowed (prob ~0), contribute 0 instead of NaN
    const float inv1 = ss.x > 0.0f ? __builtin_amdgcn_rcpf(ss.x) : 0.0f;
    const float inv2 = ss.y > 0.0f ? __builtin_amdgcn_rcpf(ss.y) : 0.0f;

    // ---- normalize + merge the two points' contributions ----
    float mg[NCODE];
#pragma unroll
    for (int j = 0; j < NCODE; ++j)
        mg[j] = fmaf(e[j].y, inv2, __fmul_rn(e[j].x, inv1));

    // ---- compacted butterfly: 63 shuffles; lane k ends owning wave-sum of bin k ----
    const int lane = t & 63;
#pragma unroll
    for (int step = 32; step >= 1; step >>= 1) {
        const bool upper = (lane & step) != 0;
#pragma unroll
        for (int i = 0; i < step; ++i) {
            float lo = mg[i], hi = mg[i + step];
            float send = upper ? lo : hi;
            float keep = upper ? hi : lo;
            mg[i] = keep + __shfl_xor(send, step, 64);
        }
    }

    // ---- cross-wave combine + coalesced partial write ----
    const int wv = t >> 6;
    sred[wv][lane] = mg[0];
    __syncthreads();
    if (t < NCODE) {
        float tot = sred[0][t] + sred[1][t] + sred[2][t] + sred[3][t];
        partial[blockIdx.x * NCODE + t] = tot;
    }
}

// ---- round-4 kernel kept verbatim as small-ws fallback (needs 256 KB) ----
#define PPT4 4
__global__ __launch_bounds__(BLK, 4) void vq_main4(
    const float* __restrict__ x,
    const float* __restrict__ embed,
    float* __restrict__ out_q,
    float* __restrict__ partial)
{
    __shared__ float4 scode[NCODE];
    __shared__ float4 sfast[NCODE];
    __shared__ float  sred[BLK / 64][NCODE];

    const int t = threadIdx.x;
    if (t < NCODE) {
        float e0 = embed[2 * t];
        float e1 = embed[2 * t + 1];
        float n = __fadd_rn(__fmul_rn(e0, e0), __fmul_rn(e1, e1));
        scode[t] = make_float4(e0, e1, n, 0.0f);
        const float k20  = 20.0f * LOG2E;
        const float km10 = -10.0f * LOG2E;
        sfast[t] = make_float4(k20 * e0, k20 * e1, km10 * n, 0.0f);
    }
    __syncthreads();

    const int gid    = blockIdx.x * BLK + t;
    const int stride = gridDim.x * BLK;
    const float2* __restrict__ xp = (const float2*)x;
    float2* __restrict__ qp = (float2*)out_q;

    float2 p[PPT4]; float s[PPT4]; int idx[PPT4];
#pragma unroll
    for (int k = 0; k < PPT4; ++k) {
        idx[k] = gid + k * stride;
        p[k] = xp[idx[k]];
        s[k] = __fadd_rn(__fmul_rn(p[k].x, p[k].x), __fmul_rn(p[k].y, p[k].y));
    }

    float m[PPT4]; int best[PPT4];
#pragma unroll
    for (int k = 0; k < PPT4; ++k) { m[k] = -INFINITY; best[k] = 0; }
#pragma unroll 8
    for (int j = 0; j < NCODE; ++j) {
        float4 c = scode[j];
#pragma unroll
        for (int k = 0; k < PPT4; ++k) {
            float dot = fmaf(p[k].y, c.y, __fmul_rn(p[k].x, c.x));
            float d = __fadd_rn(fmaf(-2.0f, dot, s[k]), c.z);
            float lg = __fmul_rn(-SIGMA, d);
            if (lg > m[k]) { m[k] = lg; best[k] = j; }
        }
    }
#pragma unroll
    for (int k = 0; k < PPT4; ++k) {
        float4 cbv = scode[best[k]];
        qp[idx[k]] = make_float2(cbv.x, cbv.y);
    }

    float gref[PPT4], ssum[PPT4];
#pragma unroll
    for (int k = 0; k < PPT4; ++k) {
        gref[k] = __fmul_rn(fmaf(10.0f, s[k], m[k]), LOG2E);
        ssum[k] = 0.0f;
    }
#pragma unroll 8
    for (int j = 0; j < NCODE; ++j) {
        float4 f = sfast[j];
#pragma unroll
        for (int k = 0; k < PPT4; ++k) {
            float g = fmaf(p[k].x, f.x, fmaf(p[k].y, f.y, f.z));
            ssum[k] += __builtin_amdgcn_exp2f(g - gref[k]);
        }
    }
#pragma unroll
    for (int k = 0; k < PPT4; ++k)
        gref[k] += __builtin_amdgcn_logf(ssum[k]);

    float acc[NCODE];
#pragma unroll
    for (int j = 0; j < NCODE; ++j) {
        float4 f = sfast[j];
        float tt = 0.0f;
#pragma unroll
        for (int k = 0; k < PPT4; ++k) {
            float g = fmaf(p[k].x, f.x, fmaf(p[k].y, f.y, f.z));
            tt += __builtin_amdgcn_exp2f(g - gref[k]);
        }
        acc[j] = tt;
    }

    const int lane = t & 63;
#pragma unroll
    for (int step = 32; step >= 1; step >>= 1) {
        const bool upper = (lane & step) != 0;
#pragma unroll
        for (int i = 0; i < step; ++i) {
            float lo = acc[i], hi = acc[i + step];
            float send = upper ? lo : hi;
            float keep = upper ? hi : lo;
            acc[i] = keep + __shfl_xor(send, step, 64);
        }
    }
    const int wv = t >> 6;
    sred[wv][lane] = acc[0];
    __syncthreads();
    if (t < NCODE) {
        float tot = sred[0][t] + sred[1][t] + sred[2][t] + sred[3][t];
        partial[blockIdx.x * NCODE + t] = tot;
    }
}

// Stage 2: reduce nblk x 64 partials -> out_lik (no atomics, deterministic).
__global__ __launch_bounds__(256) void vq_reduce(
    const float* __restrict__ partial,
    float* __restrict__ out_lik,
    int nblk, float scale)
{
    __shared__ float sm[4];
    const int b = blockIdx.x;       // bin
    const int t = threadIdx.x;
    float s = 0.0f;
    for (int i = t; i < nblk; i += 256)
        s += partial[i * NCODE + b];
#pragma unroll
    for (int msk = 32; msk >= 1; msk >>= 1)
        s += __shfl_xor(s, msk, 64);
    if ((t & 63) == 0) sm[t >> 6] = s;
    __syncthreads();
    if (t == 0)
        out_lik[b] = (sm[0] + sm[1] + sm[2] + sm[3]) * scale;
}

extern "C" void kernel_launch(void* const* d_in, const int* in_sizes, int n_in,
                              void* d_out, int out_size, void* d_ws, size_t ws_size,
                              hipStream_t stream) {
    (void)n_in;
    const float* x     = (const float*)d_in[0];   // [64*32*32*32] fp32
    const float* embed = (const float*)d_in[1];   // [64*2] fp32

    const int npts = in_sizes[0] / 2;             // 1,048,576 points
    float* out_q   = (float*)d_out;               // [npts*2]
    float* out_lik = (float*)d_out + (out_size - NCODE); // [64] tail
    float* partial = (float*)d_ws;

    const int nblk = npts / (BLK * PPT);          // 2048 (needs 512 KB ws)
    const size_t need = (size_t)nblk * NCODE * sizeof(float);

    if (ws_size >= need) {
        vq_main<<<nblk, BLK, 0, stream>>>(x, embed, out_q, partial);
        vq_reduce<<<NCODE, 256, 0, stream>>>(partial, out_lik, nblk,
                                             1.0f / (float)npts);
    } else {
        const int nblk4 = npts / (BLK * PPT4);    // 1024 (256 KB ws, round-4 proven)
        vq_main4<<<nblk4, BLK, 0, stream>>>(x, embed, out_q, partial);
        vq_reduce<<<NCODE, 256, 0, stream>>>(partial, out_lik, nblk4,
                                             1.0f / (float)npts);
    }
}